// Round 4
// baseline (347.210 us; speedup 1.0000x reference)
//
#include <hip/hip_runtime.h>
#include <stdint.h>

// GLSTM: B=16, T=96, N=325, D=64, H=64. 5200 rows, 96-step recurrence.
// R6: two groups IN THE SAME WAVES. 163 blocks x 256 thr (4 waves). Each wave
// computes its 16-col slice of all six gates for group A (2*bid) AND group B
// (2*bid+1). The two groups' per-step dataflows are independent -> in-wave ILP
// hides ds_read/MFMA/trans latency without relying on a second (lockstepped)
// wave. Weights are shared between groups: one 96-VGPR fragment set serves both.
// One barrier/step (reads parity p, writes parity pn). Depth-1 register
// prefetch of x/os(t+1), reload t+2. xacc pipeline dropped (R5 proved it null);
// trans-9 elementwise kept (single-rcp cell path, merged tanh*sig(o)).

#define TT 96
#define NNROW 325
#define STEP_OFS 20800          // N*D floats per time step
#define HT_OFS 31948800
#define CT_OFS 32281600

typedef __attribute__((ext_vector_type(8))) short short8;
typedef __attribute__((ext_vector_type(4))) float f32x4;

// barrier that does NOT drain vmcnt (prefetch loads / h-stores stay in flight)
#define BAR() asm volatile("s_waitcnt lgkmcnt(0)\n\ts_barrier" ::: "memory")

__device__ __forceinline__ short f2bf(float f) {
    union { float f; uint32_t u; } v; v.f = f;
    uint32_t r = (v.u + 0x7FFFu + ((v.u >> 16) & 1u)) >> 16;
    return (short)(r & 0xFFFFu);
}
__device__ __forceinline__ float frcp(float x) { return __builtin_amdgcn_rcpf(x); }
__device__ __forceinline__ float ex2(float x)  { return __builtin_amdgcn_exp2f(x); }
__device__ __forceinline__ uint32_t cvtpk(float lo, float hi) {
    uint32_t r;
    asm("v_cvt_pk_bf16_f32 %0, %1, %2" : "=v"(r) : "v"(lo), "v"(hi));
    return r;
}

__global__ __launch_bounds__(256, 1)
void glstm_kernel(const float* __restrict__ x,
                  const float* __restrict__ o_s,
                  const float* __restrict__ U_x,
                  const float* __restrict__ V_x,
                  const float* __restrict__ b_x,
                  const float* __restrict__ U_g,
                  const float* __restrict__ V_g,
                  const float* __restrict__ b_g,
                  float* __restrict__ out)
{
    // [group][parity][16][64] bf16 tiles; 16B blocks XOR-swizzled by (row&7):
    // elem(m,k) at m*64 + ((k>>3 ^ (m&7))<<3 | (k&7))
    __shared__ __align__(16) short Xb[2][2][1024];   // 8 KB
    __shared__ __align__(16) short Ob[2][2][1024];   // 8 KB
    __shared__ __align__(16) short Hb[2][2][1024];   // 8 KB

    const int tid = threadIdx.x;
    const int g0  = blockIdx.x * 2;
    int g1 = g0 + 1; if (g1 > NNROW - 1) g1 = NNROW - 1;  // dup work, identical stores
    const int lane = tid & 63;
    const int w    = tid >> 6;          // wave -> h-col slice w*16..w*16+15
    const int q    = lane >> 4;
    const int ln   = lane & 15;

    // ---------------- weights: per-wave column-slice B-fragments ------------
    // (shared by both groups)
    short8 fWx[4][2], fWh[4][2], fGo[2][2], fGh[2][2];
    #pragma unroll
    for (int gt = 0; gt < 4; ++gt) {
        const int col = gt * 64 + w * 16 + ln;
        #pragma unroll
        for (int kb = 0; kb < 2; ++kb) {
            short8 a, b;
            #pragma unroll
            for (int j = 0; j < 8; ++j) {
                const int row = kb * 32 + q * 8 + j;
                a[j] = f2bf(U_x[(size_t)row * 256 + col]);
                b[j] = f2bf(V_x[(size_t)row * 256 + col]);
            }
            fWx[gt][kb] = a; fWh[gt][kb] = b;
        }
    }
    #pragma unroll
    for (int gt = 0; gt < 2; ++gt) {
        const int col = gt * 64 + w * 16 + ln;
        #pragma unroll
        for (int kb = 0; kb < 2; ++kb) {
            short8 a, b;
            #pragma unroll
            for (int j = 0; j < 8; ++j) {
                const int row = kb * 32 + q * 8 + j;
                a[j] = f2bf(U_g[(size_t)row * 128 + col]);
                b[j] = f2bf(V_g[(size_t)row * 128 + col]);
            }
            fGo[gt][kb] = a; fGh[gt][kb] = b;
        }
    }

    // ---------------- staging mapping (x / o_s -> LDS, coalesced) -----------
    const int sm = tid >> 4;
    const int sd = tid & 15;
    const int sr0 = g0 * 16 + sm;
    const int sb0 = sr0 / NNROW;
    const size_t sbase0 = ((size_t)(sb0 * TT) * NNROW + (sr0 - sb0 * NNROW)) * 64 + sd * 4;
    const int sr1 = g1 * 16 + sm;
    const int sb1 = sr1 / NNROW;
    const size_t sbase1 = ((size_t)(sb1 * TT) * NNROW + (sr1 - sb1 * NNROW)) * 64 + sd * 4;
    const int stofs = (sm * 64 + (((sd >> 1) ^ (sm & 7)) << 3) + (sd & 1) * 4) * 2;

    // ---------------- A-fragment read offsets (bytes, swizzled) -------------
    const int o0 = ln * 128 + (((q    ) ^ (ln & 7)) << 4);
    const int o1 = ln * 128 + (((4 + q) ^ (ln & 7)) << 4);

    // ---------------- elementwise mapping -----------------------------------
    const int ch = w * 16 + ln;
    const float NL2E = -1.44269504f;
    const float nbf  = NL2E * b_x[ch];
    const float nbi  = NL2E * b_x[64  + ch];
    const float nbo  = NL2E * b_x[128 + ch];
    const float nbu  = NL2E * b_x[192 + ch];
    const float nbgf = NL2E * b_g[ch];
    const float nbgu = NL2E * b_g[64 + ch];

    int obase0[4], obase1[4], hofs[4];
    #pragma unroll
    for (int e = 0; e < 4; ++e) {
        const int m = q * 4 + e;          // C layout: row = (lane>>4)*4 + reg
        {
            const int row = g0 * 16 + m;
            const int b = row / NNROW;
            obase0[e] = ((b * TT) * NNROW + (row - b * NNROW)) * 64 + ch;
        }
        {
            const int row = g1 * 16 + m;
            const int b = row / NNROW;
            obase1[e] = ((b * TT) * NNROW + (row - b * NNROW)) * 64 + ch;
        }
        hofs[e] = m * 64 + ((((ch >> 3) ^ (m & 7)) << 3) | (ch & 7));
    }
    float ct0[4] = {0.f, 0.f, 0.f, 0.f};
    float ct1[4] = {0.f, 0.f, 0.f, 0.f};

    // ---------------- prologue: stage t=0, zero h, prefetch t=1 -------------
    {
        float4 xa = *(const float4*)(x   + sbase0);
        float4 sa = *(const float4*)(o_s + sbase0);
        float4 xc = *(const float4*)(x   + sbase1);
        float4 sc = *(const float4*)(o_s + sbase1);
        uint2 v;
        v.x = cvtpk(xa.x, xa.y); v.y = cvtpk(xa.z, xa.w);
        *(uint2*)((char*)&Xb[0][0][0] + stofs) = v;
        v.x = cvtpk(sa.x, sa.y); v.y = cvtpk(sa.z, sa.w);
        *(uint2*)((char*)&Ob[0][0][0] + stofs) = v;
        v.x = cvtpk(xc.x, xc.y); v.y = cvtpk(xc.z, xc.w);
        *(uint2*)((char*)&Xb[1][0][0] + stofs) = v;
        v.x = cvtpk(sc.x, sc.y); v.y = cvtpk(sc.z, sc.w);
        *(uint2*)((char*)&Ob[1][0][0] + stofs) = v;
        uint2 z; z.x = 0u; z.y = 0u;
        *(uint2*)((char*)&Hb[0][0][0] + tid * 8) = z;
        *(uint2*)((char*)&Hb[1][0][0] + tid * 8) = z;
    }
    float4 xq0 = *(const float4*)(x   + sbase0 + (size_t)STEP_OFS);
    float4 oq0 = *(const float4*)(o_s + sbase0 + (size_t)STEP_OFS);
    float4 xq1 = *(const float4*)(x   + sbase1 + (size_t)STEP_OFS);
    float4 oq1 = *(const float4*)(o_s + sbase1 + (size_t)STEP_OFS);
    BAR();

    for (int t = 0; t < TT; ++t) {
        const int p  = t & 1;
        const int pn = p ^ 1;

        // ---- fragments, both groups (12 ds_read_b128) ---------------------
        const char* xb0 = (const char*)&Xb[0][0][0] + p * 2048;
        const char* ob0 = (const char*)&Ob[0][0][0] + p * 2048;
        const char* hb0 = (const char*)&Hb[0][0][0] + p * 2048;
        const char* xb1 = (const char*)&Xb[1][0][0] + p * 2048;
        const char* ob1 = (const char*)&Ob[1][0][0] + p * 2048;
        const char* hb1 = (const char*)&Hb[1][0][0] + p * 2048;
        const short8 ax00 = *(const short8*)(xb0 + o0);
        const short8 ax01 = *(const short8*)(xb0 + o1);
        const short8 ao00 = *(const short8*)(ob0 + o0);
        const short8 ao01 = *(const short8*)(ob0 + o1);
        const short8 ah00 = *(const short8*)(hb0 + o0);
        const short8 ah01 = *(const short8*)(hb0 + o1);
        const short8 ax10 = *(const short8*)(xb1 + o0);
        const short8 ax11 = *(const short8*)(xb1 + o1);
        const short8 ao10 = *(const short8*)(ob1 + o0);
        const short8 ao11 = *(const short8*)(ob1 + o1);
        const short8 ah10 = *(const short8*)(hb1 + o0);
        const short8 ah11 = *(const short8*)(hb1 + o1);

        // ---- MFMAs: 24 per group, A/B chains independent ------------------
        f32x4 aF0[4], aG0[2], aF1[4], aG1[2];
        #pragma unroll
        for (int gt = 0; gt < 4; ++gt) {
            f32x4 a = {0.f, 0.f, 0.f, 0.f};
            a = __builtin_amdgcn_mfma_f32_16x16x32_bf16(ax00, fWx[gt][0], a, 0, 0, 0);
            a = __builtin_amdgcn_mfma_f32_16x16x32_bf16(ax01, fWx[gt][1], a, 0, 0, 0);
            a = __builtin_amdgcn_mfma_f32_16x16x32_bf16(ah00, fWh[gt][0], a, 0, 0, 0);
            aF0[gt] = __builtin_amdgcn_mfma_f32_16x16x32_bf16(ah01, fWh[gt][1], a, 0, 0, 0);
        }
        #pragma unroll
        for (int gt = 0; gt < 4; ++gt) {
            f32x4 a = {0.f, 0.f, 0.f, 0.f};
            a = __builtin_amdgcn_mfma_f32_16x16x32_bf16(ax10, fWx[gt][0], a, 0, 0, 0);
            a = __builtin_amdgcn_mfma_f32_16x16x32_bf16(ax11, fWx[gt][1], a, 0, 0, 0);
            a = __builtin_amdgcn_mfma_f32_16x16x32_bf16(ah10, fWh[gt][0], a, 0, 0, 0);
            aF1[gt] = __builtin_amdgcn_mfma_f32_16x16x32_bf16(ah11, fWh[gt][1], a, 0, 0, 0);
        }
        #pragma unroll
        for (int gt = 0; gt < 2; ++gt) {
            f32x4 a = {0.f, 0.f, 0.f, 0.f};
            a = __builtin_amdgcn_mfma_f32_16x16x32_bf16(ao00, fGo[gt][0], a, 0, 0, 0);
            a = __builtin_amdgcn_mfma_f32_16x16x32_bf16(ao01, fGo[gt][1], a, 0, 0, 0);
            a = __builtin_amdgcn_mfma_f32_16x16x32_bf16(ah00, fGh[gt][0], a, 0, 0, 0);
            aG0[gt] = __builtin_amdgcn_mfma_f32_16x16x32_bf16(ah01, fGh[gt][1], a, 0, 0, 0);
        }
        #pragma unroll
        for (int gt = 0; gt < 2; ++gt) {
            f32x4 a = {0.f, 0.f, 0.f, 0.f};
            a = __builtin_amdgcn_mfma_f32_16x16x32_bf16(ao10, fGo[gt][0], a, 0, 0, 0);
            a = __builtin_amdgcn_mfma_f32_16x16x32_bf16(ao11, fGo[gt][1], a, 0, 0, 0);
            a = __builtin_amdgcn_mfma_f32_16x16x32_bf16(ah10, fGh[gt][0], a, 0, 0, 0);
            aG1[gt] = __builtin_amdgcn_mfma_f32_16x16x32_bf16(ah11, fGh[gt][1], a, 0, 0, 0);
        }

        // ---- stage x/os(t+1) into parity pn; reload regs with t+2 ---------
        {
            uint2 v;
            v.x = cvtpk(xq0.x, xq0.y); v.y = cvtpk(xq0.z, xq0.w);
            *(uint2*)((char*)&Xb[0][0][0] + pn * 2048 + stofs) = v;
            v.x = cvtpk(oq0.x, oq0.y); v.y = cvtpk(oq0.z, oq0.w);
            *(uint2*)((char*)&Ob[0][0][0] + pn * 2048 + stofs) = v;
            v.x = cvtpk(xq1.x, xq1.y); v.y = cvtpk(xq1.z, xq1.w);
            *(uint2*)((char*)&Xb[1][0][0] + pn * 2048 + stofs) = v;
            v.x = cvtpk(oq1.x, oq1.y); v.y = cvtpk(oq1.z, oq1.w);
            *(uint2*)((char*)&Ob[1][0][0] + pn * 2048 + stofs) = v;
            int tn = t + 2; if (tn > TT - 1) tn = TT - 1;
            xq0 = *(const float4*)(x   + sbase0 + (size_t)tn * STEP_OFS);
            oq0 = *(const float4*)(o_s + sbase0 + (size_t)tn * STEP_OFS);
            xq1 = *(const float4*)(x   + sbase1 + (size_t)tn * STEP_OFS);
            oq1 = *(const float4*)(o_s + sbase1 + (size_t)tn * STEP_OFS);
        }

        // ---- elementwise, both groups (chains independent -> ILP) ---------
        const int tofs = t * STEP_OFS;
        auto ew = [&](const f32x4* aF, const f32x4* aG, float* ct,
                      const int* obase, int gg, short* hn) {
            float hv[4];
            #pragma unroll
            for (int e = 0; e < 4; ++e) {
                float ef  = ex2(fmaf(aF[0][e], NL2E, nbf));
                float ei  = ex2(fmaf(aF[1][e], NL2E, nbi));
                float eo  = ex2(fmaf(aF[2][e], NL2E, nbo));
                float eu  = ex2(fmaf(aF[3][e], NL2E, nbu));
                float egf = ex2(fmaf(aG[0][e], NL2E, nbgf));
                float egu = ex2(fmaf(aG[1][e], NL2E, nbgu));
                float P1 = (1.f + ef) * (1.f + egf);
                float P2 = (1.f + ei) * (1.f + eu) * (1.f + egu);
                float c  = fmaf(ct[e], P2, P1) * frcp(P1 * P2);
                ct[e] = c;
                float E  = ex2(fminf(c * 2.88539008f, 60.f));   // exact for tanh
                float h  = (E - 1.f) * frcp((E + 1.f) * (1.f + eo));
                hv[e] = h;
                out[obase[e] + tofs] = h;
                if (t == TT - 1) {                   // cold path: recompute fo
                    const int m = q * 4 + e;
                    const int row = gg * 16 + m;
                    const int b = row / NNROW;
                    const int f = (b * NNROW + (row - b * NNROW)) * 64 + ch;
                    out[HT_OFS + f] = h;
                    out[CT_OFS + f] = c;
                }
            }
            union { uint32_t u; short s[2]; } h01, h23;
            h01.u = cvtpk(hv[0], hv[1]);
            h23.u = cvtpk(hv[2], hv[3]);
            hn[hofs[0]] = h01.s[0];
            hn[hofs[1]] = h01.s[1];
            hn[hofs[2]] = h23.s[0];
            hn[hofs[3]] = h23.s[1];
        };
        ew(aF0, aG0, ct0, obase0, g0, (short*)((char*)&Hb[0][0][0] + pn * 2048));
        ew(aF1, aG1, ct1, obase1, g1, (short*)((char*)&Hb[1][0][0] + pn * 2048));

        BAR();  // h(t) + x/os(t+1) visible
    }
}

extern "C" void kernel_launch(void* const* d_in, const int* in_sizes, int n_in,
                              void* d_out, int out_size, void* d_ws, size_t ws_size,
                              hipStream_t stream) {
    const float* x   = (const float*)d_in[0];
    const float* o_s = (const float*)d_in[1];
    const float* U_x = (const float*)d_in[2];
    const float* V_x = (const float*)d_in[3];
    const float* b_x = (const float*)d_in[4];
    const float* U_g = (const float*)d_in[5];
    const float* V_g = (const float*)d_in[6];
    const float* b_g = (const float*)d_in[7];
    float* out = (float*)d_out;

    glstm_kernel<<<dim3(163), dim3(256), 0, stream>>>(x, o_s, U_x, V_x, b_x, U_g, V_g, b_g, out);
}